// Round 7
// baseline (32250.180 us; speedup 1.0000x reference)
//
#include <hip/hip_runtime.h>
#include <math.h>

// Problem constants
#define NB 1024      // batch
#define NH 512       // hidden
#define NT 256       // time steps
#define NCD 2        // per-step output dims

typedef unsigned short u16;
typedef __bf16 bf16x8 __attribute__((ext_vector_type(8)));
typedef float  f32x4  __attribute__((ext_vector_type(4)));

#define MFMA_BF16 __builtin_amdgcn_mfma_f32_16x16x32_bf16

__device__ __forceinline__ float sigf(float x) { return 1.0f / (1.0f + expf(-x)); }
__device__ __forceinline__ float b2f(u16 u) {
    union { unsigned i; float f; } v; v.i = ((unsigned)u) << 16; return v.f;
}
__device__ __forceinline__ u16 f2b(float f) {   // RTNE
    union { float f; unsigned i; } v; v.f = f;
    unsigned r = v.i + 0x7fffu + ((v.i >> 16) & 1u);
    return (u16)(r >> 16);
}

// async 16B global -> LDS (direct-to-shared DMA); lane L lands at base+L*16.
__device__ __forceinline__ void async_cp16(const void* gptr, void* lptr) {
    __builtin_amdgcn_global_load_lds(
        (const __attribute__((address_space(1))) unsigned int*)gptr,
        (__attribute__((address_space(3))) unsigned int*)lptr,
        16, 0, 0);
}

// ---------------------------------------------------------------------------
// 16-block group barrier, parallel-poll. Each block owns one padded flag
// (64 B apart). Arrive: release fence + store own flag = targ. Wait: lanes
// 0..15 of wave 0 poll all 16 flags concurrently (plain monotonic loads, no
// RMW). Exit: acquire fence. Generations monotonic, <=768 per run, no wrap.
// ---------------------------------------------------------------------------
__device__ __forceinline__ void flag_barrier(unsigned* flags, int blk,
                                             unsigned targ, int tid) {
    __syncthreads();
    __builtin_amdgcn_fence(__ATOMIC_RELEASE, "agent");
    if (tid < 16) {
        if (tid == blk)
            __hip_atomic_store(&flags[blk * 16], targ,
                               __ATOMIC_RELAXED, __HIP_MEMORY_SCOPE_AGENT);
        while (__hip_atomic_load(&flags[tid * 16],
                                 __ATOMIC_RELAXED, __HIP_MEMORY_SCOPE_AGENT) < targ) {}
    }
    __builtin_amdgcn_fence(__ATOMIC_ACQUIRE, "agent");
    __syncthreads();
}

// ---------------------------------------------------------------------------
// weight conversion fp32 -> bf16 (three 2048x512 LSTM weights)
// ---------------------------------------------------------------------------
__global__ __launch_bounds__(256) void convert3(
    const float* __restrict__ a, const float* __restrict__ b,
    const float* __restrict__ c,
    u16* __restrict__ oa, u16* __restrict__ ob, u16* __restrict__ oc)
{
    const int i = blockIdx.x * 256 + threadIdx.x;   // < 2048*512
    oa[i] = f2b(a[i]); ob[i] = f2b(b[i]); oc[i] = f2b(c[i]);
}

__global__ __launch_bounds__(256) void bsum_k(
    const float* __restrict__ bi1, const float* __restrict__ bh1,
    const float* __restrict__ bi2, const float* __restrict__ bh2,
    float* __restrict__ o1, float* __restrict__ o2)
{
    const int i = blockIdx.x * 256 + threadIdx.x;   // < 2048
    o1[i] = bi1[i] + bh1[i];
    o2[i] = bi2[i] + bh2[i];
}

// One-time transpose Wo1 (256x512) fp32 -> Wo1T (512x256) bf16
__global__ __launch_bounds__(256) void transpose_wo1(
    const float* __restrict__ Wo1, u16* __restrict__ Wo1T)
{
    const int idx = blockIdx.x * 256 + threadIdx.x;  // < 256*512
    const int r = idx >> 9, k = idx & 511;
    Wo1T[k * 256 + r] = f2b(Wo1[idx]);
}

// ---------------------------------------------------------------------------
// init: [h0 | c0] = z @ W_proj^T + b_proj ; h0 (bf16) -> h1,h2 ; c0 (f32)
// ---------------------------------------------------------------------------
__global__ __launch_bounds__(256) void init_kernel(
    const float* __restrict__ zp, const float* __restrict__ zs,
    const float* __restrict__ zst, const float* __restrict__ Wp,
    const float* __restrict__ bp,
    u16* __restrict__ h1, float* __restrict__ c1,
    u16* __restrict__ h2, float* __restrict__ c2)
{
    __shared__ float z[4][256];
    const int tid = threadIdx.x;
    const int b0  = blockIdx.x * 4;
    for (int i = tid; i < 4 * 256; i += 256) {
        const int bb = i >> 8, k = i & 255;
        float v;
        if (k < 64)       v = zp [(b0 + bb) * 64  + k];
        else if (k < 128) v = zs [(b0 + bb) * 64  + (k - 64)];
        else              v = zst[(b0 + bb) * 128 + (k - 128)];
        z[bb][k] = v;
    }
    __syncthreads();
    for (int rt = 0; rt < 4; ++rt) {
        const int r = rt * 256 + tid;          // 0..1023
        const float bias = bp[r];
        float a0 = bias, a1 = bias, a2 = bias, a3 = bias;
        for (int k = 0; k < 256; ++k) {
            const float w = Wp[r * 256 + k];
            a0 += z[0][k] * w; a1 += z[1][k] * w;
            a2 += z[2][k] * w; a3 += z[3][k] * w;
        }
        const float acc[4] = {a0, a1, a2, a3};
        for (int bb = 0; bb < 4; ++bb) {
            const int b = b0 + bb;
            if (r < NH) {
                h1[b * NH + r] = f2b(acc[bb]);
                h2[b * NH + r] = f2b(acc[bb]);
            } else {
                c1[b * NH + r - NH] = acc[bb];
                c2[b * NH + r - NH] = acc[bb];
            }
        }
    }
}

// ---------------------------------------------------------------------------
// LSTM phase (R4/R5-verified body). Optional group rendezvous between the
// K-loop and the epilogue (used to hide the out(t-1)->lstm1(t) barrier wait
// behind K1's MFMA work; the epilogue reads xb which out(t-1) wrote).
// ---------------------------------------------------------------------------
__device__ __forceinline__ void lstm_phase(
    char* smem,
    const u16* __restrict__ A0, const u16* __restrict__ W0,
    const u16* __restrict__ A1, const u16* __restrict__ W1,
    const float* __restrict__ bsum,
    const float* __restrict__ xin, const float* __restrict__ Wx,
    float* __restrict__ c, u16* __restrict__ hnext,
    const int npass,
    const int tid, const int lane, const int wv, const int g, const int mh,
    const int l15, const int q, const int u0, const int b0,
    const int* goff, const int* isa,
    unsigned* bar_flags, const int bar_blk, const unsigned bar_targ)
{
    float* eg = (float*)smem;

    f32x4 acc[2][2];
#pragma unroll
    for (int mi = 0; mi < 2; ++mi)
#pragma unroll
        for (int ni = 0; ni < 2; ++ni)
            acc[mi][ni] = (f32x4){0.f, 0.f, 0.f, 0.f};

    const int M = npass * 8;            // total macro-tiles

    auto issue = [&](int m) {
        const u16* __restrict__ Ap = (m < 8) ? A0 : A1;
        const u16* __restrict__ Wp = (m < 8) ? W0 : W1;
        const int k0 = (m & 7) * 64;
        char* base = smem + (m & 1) * 24576;
#pragma unroll
        for (int i = 0; i < 3; ++i) {
            const u16* gp = (isa[i] ? Ap : Wp) + (goff[i] + k0);
            async_cp16((const void*)gp, (void*)(base + ((wv * 3 + i) << 10)));
        }
    };

    issue(0);
    for (int m = 0; m < M; ++m) {
        __syncthreads();                 // drains vmcnt: loads(m) complete
        if (m + 1 < M) issue(m + 1);     // prefetch into other buffer
        const char* bA = smem + (m & 1) * 24576;
        const char* bW = bA + 8192;
#pragma unroll
        for (int khi = 0; khi < 2; ++khi) {
            bf16x8 bfr[2];
#pragma unroll
            for (int ni = 0; ni < 2; ++ni) {
                const int wrow = g * 32 + ni * 16 + l15;
                const int j = (khi * 4 + q) ^ (wrow & 7);
                bfr[ni] = *(const bf16x8*)(bW + wrow * 128 + j * 16);
            }
#pragma unroll
            for (int mi = 0; mi < 2; ++mi) {
                const int row = mh * 32 + mi * 16 + l15;
                const int j = (khi * 4 + q) ^ (row & 7);
                const bf16x8 av = *(const bf16x8*)(bA + row * 128 + j * 16);
                acc[mi][0] = MFMA_BF16(av, bfr[0], acc[mi][0], 0, 0, 0);
                acc[mi][1] = MFMA_BF16(av, bfr[1], acc[mi][1], 0, 0, 0);
            }
        }
    }

    // rendezvous (or plain sync) before LDS reuse + xb read
    if (bar_flags) flag_barrier(bar_flags, bar_blk, bar_targ, tid);
    else           __syncthreads();

    // dump gate pre-activations: eg[g][b_local][u_local], stride 33
    // C/D layout: row(batch) = q*4+r, col(unit) = l15   [m89-verified]
#pragma unroll
    for (int mi = 0; mi < 2; ++mi)
#pragma unroll
        for (int ni = 0; ni < 2; ++ni)
#pragma unroll
            for (int r = 0; r < 4; ++r)
                eg[(g * 64 + mh * 32 + mi * 16 + q * 4 + r) * 33 + ni * 16 + l15]
                    = acc[mi][ni][r];
    __syncthreads();

    // fused pointwise cell update: thread -> unit u, 4 batch rows
    const int u  = tid & 31;
    const int bg = tid >> 5;            // 0..15
    const int ug = u0 + u;
    float bs[4], wx0[4], wx1[4];
#pragma unroll
    for (int g4 = 0; g4 < 4; ++g4) bs[g4] = bsum[g4 * NH + ug];
    if (Wx) {
#pragma unroll
        for (int g4 = 0; g4 < 4; ++g4) {
            wx0[g4] = Wx[(g4 * NH + ug) * 2 + 0];
            wx1[g4] = Wx[(g4 * NH + ug) * 2 + 1];
        }
    }
#pragma unroll
    for (int jj = 0; jj < 4; ++jj) {
        const int bl = bg * 4 + jj;
        const int b  = b0 + bl;
        float gv[4];
#pragma unroll
        for (int g4 = 0; g4 < 4; ++g4) gv[g4] = eg[(g4 * 64 + bl) * 33 + u] + bs[g4];
        if (Wx) {
            const float x0 = xin[b * 2], x1 = xin[b * 2 + 1];
#pragma unroll
            for (int g4 = 0; g4 < 4; ++g4) gv[g4] += x0 * wx0[g4] + x1 * wx1[g4];
        }
        const float iv = sigf(gv[0]);
        const float fv = sigf(gv[1]);
        const float gg = tanhf(gv[2]);
        const float ov = sigf(gv[3]);
        const size_t idx = (size_t)b * NH + ug;
        const float cn = fv * c[idx] + iv * gg;
        c[idx] = cn;
        hnext[idx] = f2b(ov * tanhf(cn));
    }
}

// ---------------------------------------------------------------------------
// Out phase (R5-verified fp32 math; Wo1T now bf16, unroll 16 for L2 latency).
// thread t: neuron n = t&255, row-pair hh = t>>8 (4 batch rows per block).
// Trailing __syncthreads protects hsh/red from the next phase's LDS DMA
// (the barrier that used to follow this phase is now deferred into lstm1).
// ---------------------------------------------------------------------------
__device__ __forceinline__ void out_phase(
    char* smem, const u16* __restrict__ h2, const u16* __restrict__ W1t,
    const float* __restrict__ bo1, const float* __restrict__ Wo2,
    const float* __restrict__ bo2, float* __restrict__ xbuf,
    float* __restrict__ outp, const int t, const int tid, const int r0)
{
    float* hsh = (float*)smem;            // [4][512] fp32 = 8 KB
    float* red = (float*)(smem + 8192);   // [8 waves][4] = 128 B
    for (int i = tid; i < 4 * NH; i += 512)
        hsh[i] = b2f(h2[(size_t)(r0 + (i >> 9)) * NH + (i & 511)]);
    __syncthreads();

    const int n  = tid & 255;
    const int hh = tid >> 8;              // 0..1 -> rows hh*2, hh*2+1
    const float* hr0 = hsh + (hh * 2) * NH;
    const float* hr1 = hr0 + NH;
    float a0 = 0.f, a1 = 0.f;
#pragma unroll 16
    for (int k = 0; k < NH; ++k) {
        const float w = b2f(W1t[k * 256 + n]);   // coalesced, L2-hot
        a0 += hr0[k] * w;
        a1 += hr1[k] * w;
    }
    const float bn = bo1[n], w20 = Wo2[n], w21 = Wo2[256 + n];
    const float s0 = fmaxf(a0 + bn, 0.f), s1 = fmaxf(a1 + bn, 0.f);
    float p[4] = { s0 * w20, s0 * w21, s1 * w20, s1 * w21 };
#pragma unroll
    for (int off = 32; off > 0; off >>= 1)
#pragma unroll
        for (int r = 0; r < 4; ++r) p[r] += __shfl_down(p[r], off, 64);
    if ((tid & 63) == 0)
#pragma unroll
        for (int r = 0; r < 4; ++r) red[(tid >> 6) * 4 + r] = p[r];
    __syncthreads();
    if (tid < 8) {
        const int hh2 = tid >> 2, rp = (tid >> 1) & 1, cc = tid & 1;
        float y = bo2[cc];
#pragma unroll
        for (int wq = 0; wq < 4; ++wq)
            y += red[(hh2 * 4 + wq) * 4 + rp * 2 + cc];
        const int b = r0 + hh2 * 2 + rp;
        xbuf[b * NCD + cc] = y;
        outp[(size_t)b * (NT * NCD) + t * NCD + cc] = y;
    }
    __syncthreads();   // protect hsh/red before next phase's DMA (bar3 deferred)
}

// ---------------------------------------------------------------------------
// Persistent kernel: whole T-loop in one cooperative launch.
// 256 blocks x 512 threads (known-good launch config). XCD-local groups:
// bx -> (x = bx&7 [XCD], s = (bx>>3)&15, half = bx>>7); grp = x*2+half,
// ut = s  -- a grp's 16 blocks share an XCD (perf-only heuristic; barrier
// flags and h-tiles then hit XCD-local L2). Barriers: flag_barrier, 3/step,
// one deferred into lstm1's K-loop shadow.
// ---------------------------------------------------------------------------
__global__ __launch_bounds__(512, 1) void persistent_kernel(
    u16* h1a, u16* h1b, u16* h2a, u16* h2b,
    float* c1, float* c2, float* xb,
    const float* bs1, const float* bs2, const u16* Wo1T,
    const u16* Whh1b, const u16* Wih2b, const u16* Whh2b,
    const float* Wih1, const float* Wo2, const float* bo1, const float* bo2,
    float* outp, unsigned* barr)
{
    __shared__ __align__(16) char smem[49152];

    const int tid  = threadIdx.x;
    const int lane = tid & 63;
    const int wv   = tid >> 6;
    const int g    = wv & 3;
    const int mh   = wv >> 2;
    const int l15  = lane & 15;
    const int q    = lane >> 4;
    const int bx   = blockIdx.x;
    const int x    = bx & 7;              // XCD (heuristic)
    const int s    = (bx >> 3) & 15;
    const int half = bx >> 7;
    const int grp  = x * 2 + half;        // 0..15, members share XCD
    const int ut   = s;                   // 0..15
    const int b0   = grp * 64;
    const int u0   = ut * 32;
    const int r0   = grp * 64 + ut * 4;   // out-phase rows
    unsigned* flags = barr + grp * 256;   // 16 blocks x 16 u32 (64B padded)

    // staging descriptors (phase-independent): 1536 chunks per macro
    int goff[3], isa[3];
#pragma unroll
    for (int i = 0; i < 3; ++i) {
        const int cidx = (wv * 3 + i) * 64 + lane;   // 0..1535
        if (cidx < 512) {
            const int row = cidx >> 3;
            const int kc  = (cidx & 7) ^ (row & 7);
            goff[i] = (b0 + row) * NH + kc * 8;
            isa[i]  = 1;
        } else {
            const int rc   = cidx - 512;
            const int wrow = rc >> 3;                // g*32+uu
            const int kc   = (rc & 7) ^ (wrow & 7);
            goff[i] = ((wrow >> 5) * NH + u0 + (wrow & 31)) * NH + kc * 8;
            isa[i]  = 0;
        }
    }

    u16 *h1c = h1a, *h1n = h1b, *h2c = h2a, *h2n = h2b;
    unsigned targ = 0;
    for (int t = 0; t < NT; ++t) {
        // lstm1: K-loop, then deferred rendezvous (waits for out(t-1)'s xb),
        // then epilogue reading xb.
        lstm_phase(smem, h1c, Whh1b, (const u16*)0, (const u16*)0,
                   bs1, xb, Wih1, c1, h1n, 1,
                   tid, lane, wv, g, mh, l15, q, u0, b0, goff, isa,
                   flags, ut, ++targ);
        flag_barrier(flags, ut, ++targ, tid);        // h1n visible to all uts
        lstm_phase(smem, h1n, Wih2b, h2c, Whh2b,
                   bs2, (const float*)0, (const float*)0, c2, h2n, 2,
                   tid, lane, wv, g, mh, l15, q, u0, b0, goff, isa,
                   (unsigned*)0, 0, 0u);
        flag_barrier(flags, ut, ++targ, tid);        // h2n visible to all uts
        out_phase(smem, h2n, Wo1T, bo1, Wo2, bo2, xb, outp, t, tid, r0);
        // no barrier here: rendezvous deferred into lstm1(t+1)
        u16* tmp = h1c; h1c = h1n; h1n = tmp;
        tmp = h2c; h2c = h2n; h2n = tmp;
    }
}

// ---------------------------------------------------------------------------
extern "C" void kernel_launch(void* const* d_in, const int* in_sizes, int n_in,
                              void* d_out, int out_size, void* d_ws, size_t ws_size,
                              hipStream_t stream)
{
    const float* zp   = (const float*)d_in[0];
    const float* zsk  = (const float*)d_in[1];
    const float* zst  = (const float*)d_in[2];
    const float* Wp   = (const float*)d_in[3];
    const float* bp   = (const float*)d_in[4];
    const float* Wih1 = (const float*)d_in[5];
    const float* Whh1 = (const float*)d_in[6];
    const float* bih1 = (const float*)d_in[7];
    const float* bhh1 = (const float*)d_in[8];
    const float* Wih2 = (const float*)d_in[9];
    const float* Whh2 = (const float*)d_in[10];
    const float* bih2 = (const float*)d_in[11];
    const float* bhh2 = (const float*)d_in[12];
    const float* Wo1  = (const float*)d_in[13];
    const float* bo1  = (const float*)d_in[14];
    const float* Wo2  = (const float*)d_in[15];
    const float* bo2  = (const float*)d_in[16];

    const size_t BH = (size_t)NB * NH;          // 524288
    u16*   h1a   = (u16*)d_ws;
    u16*   h1b   = h1a + BH;
    u16*   h2a   = h1b + BH;
    u16*   h2b   = h2a + BH;
    float* c1    = (float*)(h2b + BH);
    float* c2    = c1 + BH;
    float* xb    = c2 + BH;                     // 2048 used (pad 4096)
    float* bs1   = xb + 4096;                   // 2048
    float* bs2   = bs1 + 2048;                  // 2048
    u16*   Wo1T  = (u16*)(bs2 + 2048);          // 131072 u16
    u16*   Whh1b = Wo1T + 131072;               // 1048576 each
    u16*   Wih2b = Whh1b + 1048576;
    u16*   Whh2b = Wih2b + 1048576;
    unsigned* barr = (unsigned*)(Whh2b + 1048576);  // 16 grps x 256 u32 = 16KB
    // total ~14.4 MB of d_ws

    convert3<<<(2048 * 512) / 256, 256, 0, stream>>>(Whh1, Wih2, Whh2, Whh1b, Wih2b, Whh2b);
    transpose_wo1<<<(256 * 512) / 256, 256, 0, stream>>>(Wo1, Wo1T);
    bsum_k<<<2048 / 256, 256, 0, stream>>>(bih1, bhh1, bih2, bhh2, bs1, bs2);
    hipMemsetAsync(xb, 0, NB * NCD * sizeof(float), stream);   // x0 = 0
    hipMemsetAsync(barr, 0, 16 * 256 * sizeof(unsigned), stream);
    init_kernel<<<NB / 4, 256, 0, stream>>>(zp, zsk, zst, Wp, bp, h1a, c1, h2a, c2);

    float* outp = (float*)d_out;
    void* args[] = {
        &h1a, &h1b, &h2a, &h2b, &c1, &c2, &xb, &bs1, &bs2, &Wo1T,
        &Whh1b, &Wih2b, &Whh2b, &Wih1, &Wo2, &bo1, &bo2, &outp, &barr
    };
    hipLaunchCooperativeKernel((void*)persistent_kernel,
                               dim3(256), dim3(512), args, 0, stream);
}

// Round 8
// 9057.240 us; speedup vs baseline: 3.5607x; 3.5607x over previous
//
#include <hip/hip_runtime.h>
#include <math.h>

// Problem constants
#define NB 1024      // batch
#define NH 512       // hidden
#define NT 256       // time steps
#define NCD 2        // per-step output dims

typedef unsigned short u16;
typedef __bf16 bf16x8 __attribute__((ext_vector_type(8)));
typedef float  f32x4  __attribute__((ext_vector_type(4)));

#define MFMA_BF16 __builtin_amdgcn_mfma_f32_16x16x32_bf16

__device__ __forceinline__ float sigf(float x) { return 1.0f / (1.0f + expf(-x)); }
__device__ __forceinline__ float b2f(u16 u) {
    union { unsigned i; float f; } v; v.i = ((unsigned)u) << 16; return v.f;
}
__device__ __forceinline__ u16 f2b(float f) {   // RTNE
    union { float f; unsigned i; } v; v.f = f;
    unsigned r = v.i + 0x7fffu + ((v.i >> 16) & 1u);
    return (u16)(r >> 16);
}

// async 16B global -> LDS (direct-to-shared DMA); lane L lands at base+L*16.
__device__ __forceinline__ void async_cp16(const void* gptr, void* lptr) {
    __builtin_amdgcn_global_load_lds(
        (const __attribute__((address_space(1))) unsigned int*)gptr,
        (__attribute__((address_space(3))) unsigned int*)lptr,
        16, 0, 0);
}

// ---------------------------------------------------------------------------
// weight conversion fp32 -> bf16 (three 2048x512 LSTM weights)
// ---------------------------------------------------------------------------
__global__ __launch_bounds__(256) void convert3(
    const float* __restrict__ a, const float* __restrict__ b,
    const float* __restrict__ c,
    u16* __restrict__ oa, u16* __restrict__ ob, u16* __restrict__ oc)
{
    const int i = blockIdx.x * 256 + threadIdx.x;   // < 2048*512
    oa[i] = f2b(a[i]); ob[i] = f2b(b[i]); oc[i] = f2b(c[i]);
}

__global__ __launch_bounds__(256) void bsum_k(
    const float* __restrict__ bi1, const float* __restrict__ bh1,
    const float* __restrict__ bi2, const float* __restrict__ bh2,
    float* __restrict__ o1, float* __restrict__ o2)
{
    const int i = blockIdx.x * 256 + threadIdx.x;   // < 2048
    o1[i] = bi1[i] + bh1[i];
    o2[i] = bi2[i] + bh2[i];
}

// One-time transpose Wo1 (256x512) fp32 -> Wo1T (512x256) bf16 [R7-verified]
__global__ __launch_bounds__(256) void transpose_wo1(
    const float* __restrict__ Wo1, u16* __restrict__ Wo1T)
{
    const int idx = blockIdx.x * 256 + threadIdx.x;  // < 256*512
    const int r = idx >> 9, k = idx & 511;
    Wo1T[k * 256 + r] = f2b(Wo1[idx]);
}

// ---------------------------------------------------------------------------
// init: [h0 | c0] = z @ W_proj^T + b_proj ; h0 (bf16) -> h1,h2 ; c0 (f32)
// ---------------------------------------------------------------------------
__global__ __launch_bounds__(256) void init_kernel(
    const float* __restrict__ zp, const float* __restrict__ zs,
    const float* __restrict__ zst, const float* __restrict__ Wp,
    const float* __restrict__ bp,
    u16* __restrict__ h1, float* __restrict__ c1,
    u16* __restrict__ h2, float* __restrict__ c2)
{
    __shared__ float z[4][256];
    const int tid = threadIdx.x;
    const int b0  = blockIdx.x * 4;
    for (int i = tid; i < 4 * 256; i += 256) {
        const int bb = i >> 8, k = i & 255;
        float v;
        if (k < 64)       v = zp [(b0 + bb) * 64  + k];
        else if (k < 128) v = zs [(b0 + bb) * 64  + (k - 64)];
        else              v = zst[(b0 + bb) * 128 + (k - 128)];
        z[bb][k] = v;
    }
    __syncthreads();
    for (int rt = 0; rt < 4; ++rt) {
        const int r = rt * 256 + tid;          // 0..1023
        const float bias = bp[r];
        float a0 = bias, a1 = bias, a2 = bias, a3 = bias;
        for (int k = 0; k < 256; ++k) {
            const float w = Wp[r * 256 + k];
            a0 += z[0][k] * w; a1 += z[1][k] * w;
            a2 += z[2][k] * w; a3 += z[3][k] * w;
        }
        const float acc[4] = {a0, a1, a2, a3};
        for (int bb = 0; bb < 4; ++bb) {
            const int b = b0 + bb;
            if (r < NH) {
                h1[b * NH + r] = f2b(acc[bb]);
                h2[b * NH + r] = f2b(acc[bb]);
            } else {
                c1[b * NH + r - NH] = acc[bb];
                c2[b * NH + r - NH] = acc[bb];
            }
        }
    }
}

// ---------------------------------------------------------------------------
// MFMA fused LSTM cell, BM=32 retile of the R4-verified body.
// Block tile: 32 batch x 32 units x 4 gates. 512 threads = 8 waves;
// wave = (gate g = wv&3, batch half mh = wv>>2): 1 M-frag x 2 N-frags.
// Grid: 512 blocks, 1D. XCD-aware decode: ut = (bx&7)*2 + ((bx>>3)&1),
// grp = bx>>4  -- each XCD hosts only 2 unit-slices => W working set
// ~768KB/XCD, L2-resident (perf heuristic only).
// K macro-tiles of 64, double-buffered 2 x 20KB, global_load_lds staging,
// global-side XOR bank swizzle. 40KB LDS + VGPR<=128 => 2 blocks/CU.
// ---------------------------------------------------------------------------
__global__ __launch_bounds__(512, 4) void lstm_mfma32(
    const u16* __restrict__ A0, const u16* __restrict__ W0,
    const u16* __restrict__ A1, const u16* __restrict__ W1,
    const float* __restrict__ bsum,
    const float* __restrict__ xin, const float* __restrict__ Wx,  // layer1 else null
    float* __restrict__ c, u16* __restrict__ hnext,
    const int npass)
{
    __shared__ __align__(16) char smem[40960];   // 2 x (As 4KB | Ws 16KB)
    float* eg = (float*)smem;                    // epilogue alias [4][32][33] f32

    const int tid  = threadIdx.x;
    const int lane = tid & 63;
    const int wv   = tid >> 6;          // 0..7
    const int g    = wv & 3;            // gate
    const int mh   = wv >> 2;           // batch half (16 rows)
    const int l15  = lane & 15;
    const int q    = lane >> 4;         // 0..3
    const int bx   = blockIdx.x;
    const int ut   = (bx & 7) * 2 + ((bx >> 3) & 1);  // 0..15, XCD-local pairs
    const int grp  = bx >> 4;                          // 0..31
    const int b0   = grp * 32;
    const int u0   = ut * 32;

    // staging descriptors. W: 1024 chunks -> 2 per wave (16KB);
    // A: 256 chunks -> waves 0..3 one each (4KB).
    int goffW0, goffW1, goffA = 0;
    {
        const int c0 = (wv * 2) * 64 + lane;        // 0..1023
        const int w0r = c0 >> 3;                    // g*32+uu
        goffW0 = ((w0r >> 5) * NH + u0 + (w0r & 31)) * NH + (((c0 & 7) ^ (w0r & 7)) * 8);
        const int c1i = (wv * 2 + 1) * 64 + lane;
        const int w1r = c1i >> 3;
        goffW1 = ((w1r >> 5) * NH + u0 + (w1r & 31)) * NH + (((c1i & 7) ^ (w1r & 7)) * 8);
        if (wv < 4) {
            const int ca = wv * 64 + lane;          // 0..255
            const int ar = ca >> 3;                 // batch row 0..31
            goffA = (b0 + ar) * NH + (((ca & 7) ^ (ar & 7)) * 8);
        }
    }

    f32x4 acc[2];
    acc[0] = (f32x4){0.f, 0.f, 0.f, 0.f};
    acc[1] = (f32x4){0.f, 0.f, 0.f, 0.f};

    const int M = npass * 8;

    auto issue = [&](int m) {
        const u16* __restrict__ Ap = (m < 8) ? A0 : A1;
        const u16* __restrict__ Wp = (m < 8) ? W0 : W1;
        const int k0 = (m & 7) * 64;
        char* base = smem + (m & 1) * 20480;   // As 4KB | Ws 16KB
        async_cp16((const void*)(Wp + goffW0 + k0),
                   (void*)(base + 4096 + (wv * 2) * 1024));
        async_cp16((const void*)(Wp + goffW1 + k0),
                   (void*)(base + 4096 + (wv * 2 + 1) * 1024));
        if (wv < 4)
            async_cp16((const void*)(Ap + goffA + k0),
                       (void*)(base + wv * 1024));
    };

    issue(0);
    for (int m = 0; m < M; ++m) {
        __syncthreads();                 // drains vmcnt: loads(m) complete
        if (m + 1 < M) issue(m + 1);     // prefetch into other buffer
        const char* bA = smem + (m & 1) * 20480;
        const char* bW = bA + 4096;
#pragma unroll
        for (int khi = 0; khi < 2; ++khi) {
            bf16x8 bfr[2];
#pragma unroll
            for (int ni = 0; ni < 2; ++ni) {
                const int wrow = g * 32 + ni * 16 + l15;
                const int j = (khi * 4 + q) ^ (wrow & 7);
                bfr[ni] = *(const bf16x8*)(bW + wrow * 128 + j * 16);
            }
            const int row = mh * 16 + l15;
            const int j = (khi * 4 + q) ^ (row & 7);
            const bf16x8 av = *(const bf16x8*)(bA + row * 128 + j * 16);
            acc[0] = MFMA_BF16(av, bfr[0], acc[0], 0, 0, 0);
            acc[1] = MFMA_BF16(av, bfr[1], acc[1], 0, 0, 0);
        }
    }

    __syncthreads();
    // dump gate pre-activations: eg[g][b_local][u_local], stride 33
    // C/D layout: row(batch) = q*4+r, col(unit) = l15   [m89-verified]
#pragma unroll
    for (int ni = 0; ni < 2; ++ni)
#pragma unroll
        for (int r = 0; r < 4; ++r)
            eg[(g * 32 + mh * 16 + q * 4 + r) * 33 + ni * 16 + l15] = acc[ni][r];
    __syncthreads();

    // fused pointwise cell update: thread -> unit u, 2 batch rows
    const int u  = tid & 31;
    const int bq = tid >> 5;            // 0..15
    const int ug = u0 + u;
    float bs[4], wx0[4], wx1[4];
#pragma unroll
    for (int g4 = 0; g4 < 4; ++g4) bs[g4] = bsum[g4 * NH + ug];
    if (Wx) {
#pragma unroll
        for (int g4 = 0; g4 < 4; ++g4) {
            wx0[g4] = Wx[(g4 * NH + ug) * 2 + 0];
            wx1[g4] = Wx[(g4 * NH + ug) * 2 + 1];
        }
    }
#pragma unroll
    for (int jj = 0; jj < 2; ++jj) {
        const int bl = bq * 2 + jj;
        const int b  = b0 + bl;
        float gv[4];
#pragma unroll
        for (int g4 = 0; g4 < 4; ++g4) gv[g4] = eg[(g4 * 32 + bl) * 33 + u] + bs[g4];
        if (Wx) {
            const float x0 = xin[b * 2], x1 = xin[b * 2 + 1];
#pragma unroll
            for (int g4 = 0; g4 < 4; ++g4) gv[g4] += x0 * wx0[g4] + x1 * wx1[g4];
        }
        const float iv = sigf(gv[0]);
        const float fv = sigf(gv[1]);
        const float gg = tanhf(gv[2]);
        const float ov = sigf(gv[3]);
        const size_t idx = (size_t)b * NH + ug;
        const float cn = fv * c[idx] + iv * gg;
        c[idx] = cn;
        hnext[idx] = f2b(ov * tanhf(cn));
    }
}

// ---------------------------------------------------------------------------
// out-MLP: y = relu(h2@Wo1^T+bo1)@Wo2^T+bo2.  512 blocks x 256 thr,
// 2 batch rows/block => 2 blocks/CU.  Wo1T bf16 (R7-verified math),
// unroll 16 keeps many L2 loads in flight.
// ---------------------------------------------------------------------------
__global__ __launch_bounds__(256) void out_kernel(
    const u16* __restrict__ h2, const u16* __restrict__ W1t,
    const float* __restrict__ bo1, const float* __restrict__ Wo2,
    const float* __restrict__ bo2, float* __restrict__ xbuf,
    float* __restrict__ out, const int t)
{
    __shared__ float hsh[2 * NH];         // 4 KB
    __shared__ float red[4][4];
    const int tid = threadIdx.x;
    const int b0  = blockIdx.x * 2;
    for (int i = tid; i < 2 * NH; i += 256)
        hsh[i] = b2f(h2[(size_t)b0 * NH + i]);
    __syncthreads();

    const int n = tid;                    // 0..255
    float a0 = 0.f, a1 = 0.f;
#pragma unroll 16
    for (int k = 0; k < NH; ++k) {
        const float w = b2f(W1t[k * 256 + n]);   // coalesced, L2-hot
        a0 += hsh[k] * w;
        a1 += hsh[NH + k] * w;
    }
    const float bn = bo1[n], w20 = Wo2[n], w21 = Wo2[256 + n];
    const float s0 = fmaxf(a0 + bn, 0.f), s1 = fmaxf(a1 + bn, 0.f);
    float p[4] = { s0 * w20, s0 * w21, s1 * w20, s1 * w21 };
#pragma unroll
    for (int off = 32; off > 0; off >>= 1)
#pragma unroll
        for (int r = 0; r < 4; ++r) p[r] += __shfl_down(p[r], off, 64);
    const int wave = tid >> 6, lane = tid & 63;
    if (lane == 0)
#pragma unroll
        for (int r = 0; r < 4; ++r) red[r][wave] = p[r];
    __syncthreads();
    if (tid < 4) {
        const int rp = tid >> 1, cc = tid & 1;   // row, out-dim
        const float v = red[tid][0] + red[tid][1] + red[tid][2] + red[tid][3]
                        + bo2[cc];
        const int b = b0 + rp;
        xbuf[b * NCD + cc] = v;
        out[(size_t)b * (NT * NCD) + t * NCD + cc] = v;
    }
}

// ---------------------------------------------------------------------------
extern "C" void kernel_launch(void* const* d_in, const int* in_sizes, int n_in,
                              void* d_out, int out_size, void* d_ws, size_t ws_size,
                              hipStream_t stream)
{
    const float* zp   = (const float*)d_in[0];
    const float* zsk  = (const float*)d_in[1];
    const float* zst  = (const float*)d_in[2];
    const float* Wp   = (const float*)d_in[3];
    const float* bp   = (const float*)d_in[4];
    const float* Wih1 = (const float*)d_in[5];
    const float* Whh1 = (const float*)d_in[6];
    const float* bih1 = (const float*)d_in[7];
    const float* bhh1 = (const float*)d_in[8];
    const float* Wih2 = (const float*)d_in[9];
    const float* Whh2 = (const float*)d_in[10];
    const float* bih2 = (const float*)d_in[11];
    const float* bhh2 = (const float*)d_in[12];
    const float* Wo1  = (const float*)d_in[13];
    const float* bo1  = (const float*)d_in[14];
    const float* Wo2  = (const float*)d_in[15];
    const float* bo2  = (const float*)d_in[16];

    const size_t BH = (size_t)NB * NH;          // 524288
    u16*   h1a   = (u16*)d_ws;
    u16*   h1b   = h1a + BH;
    u16*   h2a   = h1b + BH;
    u16*   h2b   = h2a + BH;
    float* c1    = (float*)(h2b + BH);
    float* c2    = c1 + BH;
    float* xb    = c2 + BH;                     // 2048 used (pad 4096)
    float* bs1   = xb + 4096;                   // 2048
    float* bs2   = bs1 + 2048;                  // 2048
    u16*   Wo1T  = (u16*)(bs2 + 2048);          // 131072 u16
    u16*   Whh1b = Wo1T + 131072;               // 1048576 each
    u16*   Wih2b = Whh1b + 1048576;
    u16*   Whh2b = Wih2b + 1048576;
    // total ~14.4 MB of d_ws

    convert3<<<(2048 * 512) / 256, 256, 0, stream>>>(Whh1, Wih2, Whh2, Whh1b, Wih2b, Whh2b);
    transpose_wo1<<<(256 * 512) / 256, 256, 0, stream>>>(Wo1, Wo1T);
    bsum_k<<<2048 / 256, 256, 0, stream>>>(bih1, bhh1, bih2, bhh2, bs1, bs2);
    hipMemsetAsync(xb, 0, NB * NCD * sizeof(float), stream);   // x0 = 0
    init_kernel<<<NB / 4, 256, 0, stream>>>(zp, zsk, zst, Wp, bp, h1a, c1, h2a, c2);

    u16* h1c = h1a; u16* h1n = h1b;
    u16* h2c = h2a; u16* h2n = h2b;
    float* outp = (float*)d_out;
    for (int t = 0; t < NT; ++t) {
        lstm_mfma32<<<512, 512, 0, stream>>>(h1c, Whh1b, (const u16*)0, (const u16*)0,
                                             bs1, xb, Wih1, c1, h1n, 1);
        lstm_mfma32<<<512, 512, 0, stream>>>(h1n, Wih2b, h2c, Whh2b,
                                             bs2, (const float*)0, (const float*)0, c2, h2n, 2);
        out_kernel<<<512, 256, 0, stream>>>(h2n, Wo1T, bo1, Wo2, bo2, xb, outp, t);
        u16* tmp = h1c; h1c = h1n; h1n = tmp;
        tmp = h2c; h2c = h2n; h2n = tmp;
    }
}

// Round 9
// 8472.446 us; speedup vs baseline: 3.8065x; 1.0690x over previous
//
#include <hip/hip_runtime.h>
#include <math.h>

// Problem constants
#define NB 1024      // batch
#define NH 512       // hidden
#define NT 256       // time steps
#define NCD 2        // per-step output dims

typedef unsigned short u16;
typedef __bf16 bf16x8 __attribute__((ext_vector_type(8)));
typedef float  f32x4  __attribute__((ext_vector_type(4)));

#define MFMA_BF16 __builtin_amdgcn_mfma_f32_16x16x32_bf16

__device__ __forceinline__ float sigf(float x) { return 1.0f / (1.0f + expf(-x)); }
__device__ __forceinline__ float b2f(u16 u) {
    union { unsigned i; float f; } v; v.i = ((unsigned)u) << 16; return v.f;
}
__device__ __forceinline__ u16 f2b(float f) {   // RTNE
    union { float f; unsigned i; } v; v.f = f;
    unsigned r = v.i + 0x7fffu + ((v.i >> 16) & 1u);
    return (u16)(r >> 16);
}

// async 16B global -> LDS (direct-to-shared DMA); lane L lands at base+L*16.
__device__ __forceinline__ void async_cp16(const void* gptr, void* lptr) {
    __builtin_amdgcn_global_load_lds(
        (const __attribute__((address_space(1))) unsigned int*)gptr,
        (__attribute__((address_space(3))) unsigned int*)lptr,
        16, 0, 0);
}

// ---------------------------------------------------------------------------
// weight conversion fp32 -> bf16 (three 2048x512 LSTM weights)
// ---------------------------------------------------------------------------
__global__ __launch_bounds__(256) void convert3(
    const float* __restrict__ a, const float* __restrict__ b,
    const float* __restrict__ c,
    u16* __restrict__ oa, u16* __restrict__ ob, u16* __restrict__ oc)
{
    const int i = blockIdx.x * 256 + threadIdx.x;   // < 2048*512
    oa[i] = f2b(a[i]); ob[i] = f2b(b[i]); oc[i] = f2b(c[i]);
}

__global__ __launch_bounds__(256) void bsum_k(
    const float* __restrict__ bi1, const float* __restrict__ bh1,
    const float* __restrict__ bi2, const float* __restrict__ bh2,
    float* __restrict__ o1, float* __restrict__ o2)
{
    const int i = blockIdx.x * 256 + threadIdx.x;   // < 2048
    o1[i] = bi1[i] + bh1[i];
    o2[i] = bi2[i] + bh2[i];
}

// One-time transpose Wo1 (256x512) fp32 -> Wo1T (512x256) bf16 [R7-verified]
__global__ __launch_bounds__(256) void transpose_wo1(
    const float* __restrict__ Wo1, u16* __restrict__ Wo1T)
{
    const int idx = blockIdx.x * 256 + threadIdx.x;  // < 256*512
    const int r = idx >> 9, k = idx & 511;
    Wo1T[k * 256 + r] = f2b(Wo1[idx]);
}

// ---------------------------------------------------------------------------
// init: [h0 | c0] = z @ W_proj^T + b_proj ; h0 (bf16) -> h1,h2 ; c0 (f32)
// ---------------------------------------------------------------------------
__global__ __launch_bounds__(256) void init_kernel(
    const float* __restrict__ zp, const float* __restrict__ zs,
    const float* __restrict__ zst, const float* __restrict__ Wp,
    const float* __restrict__ bp,
    u16* __restrict__ h1, float* __restrict__ c1,
    u16* __restrict__ h2, float* __restrict__ c2)
{
    __shared__ float z[4][256];
    const int tid = threadIdx.x;
    const int b0  = blockIdx.x * 4;
    for (int i = tid; i < 4 * 256; i += 256) {
        const int bb = i >> 8, k = i & 255;
        float v;
        if (k < 64)       v = zp [(b0 + bb) * 64  + k];
        else if (k < 128) v = zs [(b0 + bb) * 64  + (k - 64)];
        else              v = zst[(b0 + bb) * 128 + (k - 128)];
        z[bb][k] = v;
    }
    __syncthreads();
    for (int rt = 0; rt < 4; ++rt) {
        const int r = rt * 256 + tid;          // 0..1023
        const float bias = bp[r];
        float a0 = bias, a1 = bias, a2 = bias, a3 = bias;
        for (int k = 0; k < 256; ++k) {
            const float w = Wp[r * 256 + k];
            a0 += z[0][k] * w; a1 += z[1][k] * w;
            a2 += z[2][k] * w; a3 += z[3][k] * w;
        }
        const float acc[4] = {a0, a1, a2, a3};
        for (int bb = 0; bb < 4; ++bb) {
            const int b = b0 + bb;
            if (r < NH) {
                h1[b * NH + r] = f2b(acc[bb]);
                h2[b * NH + r] = f2b(acc[bb]);
            } else {
                c1[b * NH + r - NH] = acc[bb];
                c2[b * NH + r - NH] = acc[bb];
            }
        }
    }
}

// ---------------------------------------------------------------------------
// MFMA fused LSTM cell, BM=32, triple-buffered depth-2 prefetch.
// Block tile: 32 batch x 32 units x 4 gates. 512 threads = 8 waves;
// wave = (gate g = wv&3, batch half mh = wv>>2): 1 M-frag x 2 N-frags.
// Grid: 512 blocks; XCD-aware decode ut=(bx&7)*2+((bx>>3)&1), grp=bx>>4.
// K macro-tiles of 64; 3 x 20KB LDS buffers; macro m+2 issued while macro m
// computes. Manual s_waitcnt vmcnt(N) (keep newer macro's loads in flight,
// in-order retirement) + raw s_barrier replaces the draining __syncthreads.
// Waves 0-3 issue 3 loads/macro (2W+1A), waves 4-7 issue 2 (2W).
// ---------------------------------------------------------------------------
__global__ __launch_bounds__(512, 4) void lstm_mfma32(
    const u16* __restrict__ A0, const u16* __restrict__ W0,
    const u16* __restrict__ A1, const u16* __restrict__ W1,
    const float* __restrict__ bsum,
    const float* __restrict__ xin, const float* __restrict__ Wx,  // layer1 else null
    float* __restrict__ c, u16* __restrict__ hnext,
    const int npass)
{
    __shared__ __align__(16) char smem[61440];   // 3 x (As 4KB | Ws 16KB)
    float* eg = (float*)smem;                    // epilogue alias [4][32][33] f32

    const int tid  = threadIdx.x;
    const int lane = tid & 63;
    const int wv   = tid >> 6;          // 0..7
    const int g    = wv & 3;            // gate
    const int mh   = wv >> 2;           // batch half (16 rows)
    const int l15  = lane & 15;
    const int q    = lane >> 4;         // 0..3
    const int bx   = blockIdx.x;
    const int ut   = (bx & 7) * 2 + ((bx >> 3) & 1);  // 0..15, XCD-local pairs
    const int grp  = bx >> 4;                          // 0..31
    const int b0   = grp * 32;
    const int u0   = ut * 32;

    // staging descriptors. W: 1024 chunks -> 2 per wave (16KB);
    // A: 256 chunks -> waves 0..3 one each (4KB).
    int goffW0, goffW1, goffA = 0;
    {
        const int c0 = (wv * 2) * 64 + lane;        // 0..1023
        const int w0r = c0 >> 3;                    // g*32+uu
        goffW0 = ((w0r >> 5) * NH + u0 + (w0r & 31)) * NH + (((c0 & 7) ^ (w0r & 7)) * 8);
        const int c1i = (wv * 2 + 1) * 64 + lane;
        const int w1r = c1i >> 3;
        goffW1 = ((w1r >> 5) * NH + u0 + (w1r & 31)) * NH + (((c1i & 7) ^ (w1r & 7)) * 8);
        if (wv < 4) {
            const int ca = wv * 64 + lane;          // 0..255
            const int ar = ca >> 3;                 // batch row 0..31
            goffA = (b0 + ar) * NH + (((ca & 7) ^ (ar & 7)) * 8);
        }
    }

    f32x4 acc[2];
    acc[0] = (f32x4){0.f, 0.f, 0.f, 0.f};
    acc[1] = (f32x4){0.f, 0.f, 0.f, 0.f};

    const int M = npass * 8;

    auto issue = [&](int m, int bi) {
        const u16* __restrict__ Ap = (m < 8) ? A0 : A1;
        const u16* __restrict__ Wp = (m < 8) ? W0 : W1;
        const int k0 = (m & 7) * 64;
        char* base = smem + bi * 20480;        // As 4KB | Ws 16KB
        async_cp16((const void*)(Wp + goffW0 + k0),
                   (void*)(base + 4096 + (wv * 2) * 1024));
        async_cp16((const void*)(Wp + goffW1 + k0),
                   (void*)(base + 4096 + (wv * 2 + 1) * 1024));
        if (wv < 4)
            async_cp16((const void*)(Ap + goffA + k0),
                       (void*)(base + wv * 1024));
    };

    issue(0, 0);
    if (M > 1) issue(1, 1);
    int ci = 0;                          // buffer index of macro m
    for (int m = 0; m < M; ++m) {
        // wait: macro m's loads retired; keep macro m+1's (3 or 2) in flight
        if (m + 1 < M) {
            if (wv < 4) asm volatile("s_waitcnt vmcnt(3)" ::: "memory");
            else        asm volatile("s_waitcnt vmcnt(2)" ::: "memory");
        } else {
            asm volatile("s_waitcnt vmcnt(0)" ::: "memory");
        }
        __builtin_amdgcn_s_barrier();    // all waves' macro-m tiles in LDS
        if (m + 2 < M) {
            int bi = ci + 2; if (bi >= 3) bi -= 3;
            issue(m + 2, bi);            // into buffer last read at iter m-1
        }
        const char* bA = smem + ci * 20480;
        const char* bW = bA + 4096;
#pragma unroll
        for (int khi = 0; khi < 2; ++khi) {
            bf16x8 bfr[2];
#pragma unroll
            for (int ni = 0; ni < 2; ++ni) {
                const int wrow = g * 32 + ni * 16 + l15;
                const int j = (khi * 4 + q) ^ (wrow & 7);
                bfr[ni] = *(const bf16x8*)(bW + wrow * 128 + j * 16);
            }
            const int row = mh * 16 + l15;
            const int j = (khi * 4 + q) ^ (row & 7);
            const bf16x8 av = *(const bf16x8*)(bA + row * 128 + j * 16);
            acc[0] = MFMA_BF16(av, bfr[0], acc[0], 0, 0, 0);
            acc[1] = MFMA_BF16(av, bfr[1], acc[1], 0, 0, 0);
        }
        ++ci; if (ci == 3) ci = 0;
    }

    __syncthreads();
    // dump gate pre-activations: eg[g][b_local][u_local], stride 33
    // C/D layout: row(batch) = q*4+r, col(unit) = l15   [m89-verified]
#pragma unroll
    for (int ni = 0; ni < 2; ++ni)
#pragma unroll
        for (int r = 0; r < 4; ++r)
            eg[(g * 32 + mh * 16 + q * 4 + r) * 33 + ni * 16 + l15] = acc[ni][r];
    __syncthreads();

    // fused pointwise cell update: thread -> unit u, 2 batch rows
    const int u  = tid & 31;
    const int bq = tid >> 5;            // 0..15
    const int ug = u0 + u;
    float bs[4], wx0[4], wx1[4];
#pragma unroll
    for (int g4 = 0; g4 < 4; ++g4) bs[g4] = bsum[g4 * NH + ug];
    if (Wx) {
#pragma unroll
        for (int g4 = 0; g4 < 4; ++g4) {
            wx0[g4] = Wx[(g4 * NH + ug) * 2 + 0];
            wx1[g4] = Wx[(g4 * NH + ug) * 2 + 1];
        }
    }
#pragma unroll
    for (int jj = 0; jj < 2; ++jj) {
        const int bl = bq * 2 + jj;
        const int b  = b0 + bl;
        float gv[4];
#pragma unroll
        for (int g4 = 0; g4 < 4; ++g4) gv[g4] = eg[(g4 * 32 + bl) * 33 + u] + bs[g4];
        if (Wx) {
            const float x0 = xin[b * 2], x1 = xin[b * 2 + 1];
#pragma unroll
            for (int g4 = 0; g4 < 4; ++g4) gv[g4] += x0 * wx0[g4] + x1 * wx1[g4];
        }
        const float iv = sigf(gv[0]);
        const float fv = sigf(gv[1]);
        const float gg = tanhf(gv[2]);
        const float ov = sigf(gv[3]);
        const size_t idx = (size_t)b * NH + ug;
        const float cn = fv * c[idx] + iv * gg;
        c[idx] = cn;
        hnext[idx] = f2b(ov * tanhf(cn));
    }
}

// ---------------------------------------------------------------------------
// out-MLP: y = relu(h2@Wo1^T+bo1)@Wo2^T+bo2.  512 blocks x 256 thr,
// 2 batch rows/block => 2 blocks/CU.  Wo1T bf16 (R7-verified math),
// unroll 16 keeps many L2 loads in flight.  [R8-verified]
// ---------------------------------------------------------------------------
__global__ __launch_bounds__(256) void out_kernel(
    const u16* __restrict__ h2, const u16* __restrict__ W1t,
    const float* __restrict__ bo1, const float* __restrict__ Wo2,
    const float* __restrict__ bo2, float* __restrict__ xbuf,
    float* __restrict__ out, const int t)
{
    __shared__ float hsh[2 * NH];         // 4 KB
    __shared__ float red[4][4];
    const int tid = threadIdx.x;
    const int b0  = blockIdx.x * 2;
    for (int i = tid; i < 2 * NH; i += 256)
        hsh[i] = b2f(h2[(size_t)b0 * NH + i]);
    __syncthreads();

    const int n = tid;                    // 0..255
    float a0 = 0.f, a1 = 0.f;
#pragma unroll 16
    for (int k = 0; k < NH; ++k) {
        const float w = b2f(W1t[k * 256 + n]);   // coalesced, L2-hot
        a0 += hsh[k] * w;
        a1 += hsh[NH + k] * w;
    }
    const float bn = bo1[n], w20 = Wo2[n], w21 = Wo2[256 + n];
    const float s0 = fmaxf(a0 + bn, 0.f), s1 = fmaxf(a1 + bn, 0.f);
    float p[4] = { s0 * w20, s0 * w21, s1 * w20, s1 * w21 };
#pragma unroll
    for (int off = 32; off > 0; off >>= 1)
#pragma unroll
        for (int r = 0; r < 4; ++r) p[r] += __shfl_down(p[r], off, 64);
    const int wave = tid >> 6, lane = tid & 63;
    if (lane == 0)
#pragma unroll
        for (int r = 0; r < 4; ++r) red[r][wave] = p[r];
    __syncthreads();
    if (tid < 4) {
        const int rp = tid >> 1, cc = tid & 1;   // row, out-dim
        const float v = red[tid][0] + red[tid][1] + red[tid][2] + red[tid][3]
                        + bo2[cc];
        const int b = b0 + rp;
        xbuf[b * NCD + cc] = v;
        out[(size_t)b * (NT * NCD) + t * NCD + cc] = v;
    }
}

// ---------------------------------------------------------------------------
extern "C" void kernel_launch(void* const* d_in, const int* in_sizes, int n_in,
                              void* d_out, int out_size, void* d_ws, size_t ws_size,
                              hipStream_t stream)
{
    const float* zp   = (const float*)d_in[0];
    const float* zsk  = (const float*)d_in[1];
    const float* zst  = (const float*)d_in[2];
    const float* Wp   = (const float*)d_in[3];
    const float* bp   = (const float*)d_in[4];
    const float* Wih1 = (const float*)d_in[5];
    const float* Whh1 = (const float*)d_in[6];
    const float* bih1 = (const float*)d_in[7];
    const float* bhh1 = (const float*)d_in[8];
    const float* Wih2 = (const float*)d_in[9];
    const float* Whh2 = (const float*)d_in[10];
    const float* bih2 = (const float*)d_in[11];
    const float* bhh2 = (const float*)d_in[12];
    const float* Wo1  = (const float*)d_in[13];
    const float* bo1  = (const float*)d_in[14];
    const float* Wo2  = (const float*)d_in[15];
    const float* bo2  = (const float*)d_in[16];

    const size_t BH = (size_t)NB * NH;          // 524288
    u16*   h1a   = (u16*)d_ws;
    u16*   h1b   = h1a + BH;
    u16*   h2a   = h1b + BH;
    u16*   h2b   = h2a + BH;
    float* c1    = (float*)(h2b + BH);
    float* c2    = c1 + BH;
    float* xb    = c2 + BH;                     // 2048 used (pad 4096)
    float* bs1   = xb + 4096;                   // 2048
    float* bs2   = bs1 + 2048;                  // 2048
    u16*   Wo1T  = (u16*)(bs2 + 2048);          // 131072 u16
    u16*   Whh1b = Wo1T + 131072;               // 1048576 each
    u16*   Wih2b = Whh1b + 1048576;
    u16*   Whh2b = Wih2b + 1048576;
    // total ~14.4 MB of d_ws

    convert3<<<(2048 * 512) / 256, 256, 0, stream>>>(Whh1, Wih2, Whh2, Whh1b, Wih2b, Whh2b);
    transpose_wo1<<<(256 * 512) / 256, 256, 0, stream>>>(Wo1, Wo1T);
    bsum_k<<<2048 / 256, 256, 0, stream>>>(bih1, bhh1, bih2, bhh2, bs1, bs2);
    hipMemsetAsync(xb, 0, NB * NCD * sizeof(float), stream);   // x0 = 0
    init_kernel<<<NB / 4, 256, 0, stream>>>(zp, zsk, zst, Wp, bp, h1a, c1, h2a, c2);

    u16* h1c = h1a; u16* h1n = h1b;
    u16* h2c = h2a; u16* h2n = h2b;
    float* outp = (float*)d_out;
    for (int t = 0; t < NT; ++t) {
        lstm_mfma32<<<512, 512, 0, stream>>>(h1c, Whh1b, (const u16*)0, (const u16*)0,
                                             bs1, xb, Wih1, c1, h1n, 1);
        lstm_mfma32<<<512, 512, 0, stream>>>(h1n, Wih2b, h2c, Whh2b,
                                             bs2, (const float*)0, (const float*)0, c2, h2n, 2);
        out_kernel<<<512, 256, 0, stream>>>(h2n, Wo1T, bo1, Wo2, bo2, xb, outp, t);
        u16* tmp = h1c; h1c = h1n; h1n = tmp;
        tmp = h2c; h2c = h2n; h2n = tmp;
    }
}